// Round 3
// baseline (30.264 us; speedup 1.0000x reference)
//
#include <hip/hip_runtime.h>

// DCN cross layers, fused closed form, persistent blocks, paired rows.
// out[r,d] = x[r,d] * (1 + sum_i s_i * W[i,d]) + bsum[d]
// s_0 = T = sum_d x[r,d];  s_i = s_{i-1} * (1 + A_{i-1}) + B_{i-1}
// A_j = dot(x_r, W[j]),  B_j = sum_d b[j,d],  bsum[d] = sum_j b[j,d]

typedef float v4 __attribute__((ext_vector_type(4)));

constexpr int Bn = 8192;
constexpr int D = 2048;
constexpr int L = 4;
constexpr int THREADS = 256;
constexpr int VEC = 4;
constexpr int PASSES = D / (THREADS * VEC); // 2
constexpr int RPI = 2;                      // rows per iteration
constexpr int ITERS = 2;                    // iterations per block
constexpr int RPB = RPI * ITERS;            // 4 rows per block
constexpr int GRID = Bn / RPB;              // 2048

__device__ inline v4 ntload(const float* p) {
    return __builtin_nontemporal_load(reinterpret_cast<const v4*>(p));
}
__device__ inline void ntstore(float* p, v4 v) {
    __builtin_nontemporal_store(v, reinterpret_cast<v4*>(p));
}
__device__ inline float hsum(v4 v) { return v.x + v.y + v.z + v.w; }

__global__ __launch_bounds__(THREADS) void cross_layer_kernel(
    const float* __restrict__ x,
    const float* __restrict__ W,
    const float* __restrict__ b,
    float* __restrict__ out)
{
    const int tid = threadIdx.x;
    const int lane = tid & 63;
    const int wid = tid >> 6;

    __shared__ float redp[4][3];        // prologue: B_0..B_2
    __shared__ float red[2][4][2 * 4];  // per-iter: 2 rows x {T,A0,A1,A2}

    // ---- prologue: block-invariant W and b (cached loads; W/b are L2-hot) ----
    v4 wv[L][PASSES];
    v4 bs[PASSES];
    float bred[3] = {0.f, 0.f, 0.f};

#pragma unroll
    for (int p = 0; p < PASSES; ++p) {
        const int d = p * (THREADS * VEC) + tid * VEC;
        v4 bsum = {0.f, 0.f, 0.f, 0.f};
#pragma unroll
        for (int i = 0; i < L; ++i) {
            wv[i][p] = *reinterpret_cast<const v4*>(W + i * D + d);
            v4 bb = *reinterpret_cast<const v4*>(b + i * D + d);
            bsum += bb;
            if (i < 3) bred[i] += hsum(bb);
        }
        bs[p] = bsum;
    }

#pragma unroll
    for (int k = 0; k < 3; ++k)
#pragma unroll
        for (int off = 32; off > 0; off >>= 1)
            bred[k] += __shfl_down(bred[k], off, 64);
    if (lane == 0)
#pragma unroll
        for (int k = 0; k < 3; ++k) redp[wid][k] = bred[k];
    __syncthreads();
    float Bsc[3];
#pragma unroll
    for (int k = 0; k < 3; ++k)
        Bsc[k] = redp[0][k] + redp[1][k] + redp[2][k] + redp[3][k];

    // ---- row loop: RPI rows per iteration, prefetch next pair (nt loads) ----
    v4 xv[RPI][PASSES], xn[RPI][PASSES];
    {
        const int col = tid * VEC;
#pragma unroll
        for (int r = 0; r < RPI; ++r) {
            const float* xr = x + (size_t)(blockIdx.x + GRID * r) * D;
#pragma unroll
            for (int p = 0; p < PASSES; ++p)
                xv[r][p] = ntload(xr + p * (THREADS * VEC) + col);
        }
    }

#pragma unroll
    for (int it = 0; it < ITERS; ++it) {
        if (it + 1 < ITERS) {
            const int col = tid * VEC;
#pragma unroll
            for (int r = 0; r < RPI; ++r) {
                const float* xr = x + (size_t)(blockIdx.x + GRID * (RPI * (it + 1) + r)) * D;
#pragma unroll
                for (int p = 0; p < PASSES; ++p)
                    xn[r][p] = ntload(xr + p * (THREADS * VEC) + col);
            }
        }

        // 8 row sums: for each of 2 rows, {T, A0, A1, A2}
        float sm[RPI * 4];
#pragma unroll
        for (int q = 0; q < RPI * 4; ++q) sm[q] = 0.f;
#pragma unroll
        for (int r = 0; r < RPI; ++r)
#pragma unroll
            for (int p = 0; p < PASSES; ++p) {
                sm[r * 4 + 0] += hsum(xv[r][p]);
#pragma unroll
                for (int i = 0; i < 3; ++i)
                    sm[r * 4 + 1 + i] += hsum(xv[r][p] * wv[i][p]);
            }

#pragma unroll
        for (int q = 0; q < RPI * 4; ++q)
#pragma unroll
            for (int off = 32; off > 0; off >>= 1)
                sm[q] += __shfl_down(sm[q], off, 64);

        if (lane == 0)
#pragma unroll
            for (int q = 0; q < RPI * 4; ++q) red[it & 1][wid][q] = sm[q];
        __syncthreads();   // single barrier: next iter writes the OTHER buffer

        float s[RPI][L];
#pragma unroll
        for (int r = 0; r < RPI; ++r) {
            const float T  = red[it & 1][0][r * 4] + red[it & 1][1][r * 4]
                           + red[it & 1][2][r * 4] + red[it & 1][3][r * 4];
            float A[3];
#pragma unroll
            for (int q = 0; q < 3; ++q)
                A[q] = red[it & 1][0][r * 4 + 1 + q] + red[it & 1][1][r * 4 + 1 + q]
                     + red[it & 1][2][r * 4 + 1 + q] + red[it & 1][3][r * 4 + 1 + q];
            s[r][0] = T;
#pragma unroll
            for (int i = 1; i < L; ++i)
                s[r][i] = s[r][i - 1] * (1.f + A[i - 1]) + Bsc[i - 1];
        }

        const int col = tid * VEC;
#pragma unroll
        for (int r = 0; r < RPI; ++r) {
            float* outr = out + (size_t)(blockIdx.x + GRID * (RPI * it + r)) * D;
#pragma unroll
            for (int p = 0; p < PASSES; ++p) {
                v4 c = {1.f, 1.f, 1.f, 1.f};
#pragma unroll
                for (int i = 0; i < L; ++i)
                    c += s[r][i] * wv[i][p];
                ntstore(outr + p * (THREADS * VEC) + col, xv[r][p] * c + bs[p]);
            }
        }

#pragma unroll
        for (int r = 0; r < RPI; ++r)
#pragma unroll
            for (int p = 0; p < PASSES; ++p)
                xv[r][p] = xn[r][p];
    }
}

extern "C" void kernel_launch(void* const* d_in, const int* in_sizes, int n_in,
                              void* d_out, int out_size, void* d_ws, size_t ws_size,
                              hipStream_t stream) {
    const float* x = (const float*)d_in[0];
    const float* W = (const float*)d_in[1];
    const float* b = (const float*)d_in[2];
    float* out = (float*)d_out;
    cross_layer_kernel<<<GRID, THREADS, 0, stream>>>(x, W, b, out);
}

// Round 4
// 26.376 us; speedup vs baseline: 1.1474x; 1.1474x over previous
//
#include <hip/hip_runtime.h>

// DCN cross layers, fused closed form, persistent blocks.
// out[r,d] = x[r,d] * (1 + sum_i s_i * W[i,d]) + bsum[d]
// s_0 = T = sum_d x[r,d];  s_i = s_{i-1} * (1 + A_{i-1}) + B_{i-1}
// A_j = dot(x_r, W[j]),  B_j = sum_d b[j,d],  bsum[d] = sum_j b[j,d]
//
// RPB=8 rows/block (halves W/b prologue L2 traffic vs RPB=4), cached
// loads/stores (x stays L3-resident across replays — nt hurt in R3),
// row-0 x loads issued before the prologue, 1 barrier/row via
// double-buffered reduce slots.

typedef float v4 __attribute__((ext_vector_type(4)));

constexpr int Bn = 8192;
constexpr int D = 2048;
constexpr int L = 4;
constexpr int THREADS = 256;
constexpr int VEC = 4;
constexpr int PASSES = D / (THREADS * VEC); // 2
constexpr int RPB = 8;                      // rows per block
constexpr int GRID = Bn / RPB;              // 1024 = 4 blocks/CU

__device__ inline float hsum(v4 v) { return v.x + v.y + v.z + v.w; }

__global__ __launch_bounds__(THREADS) void cross_layer_kernel(
    const float* __restrict__ x,
    const float* __restrict__ W,
    const float* __restrict__ b,
    float* __restrict__ out)
{
    const int tid = threadIdx.x;
    const int lane = tid & 63;
    const int wid = tid >> 6;
    const int col = tid * VEC;

    __shared__ float redp[4][3];     // prologue: B_0..B_2 partials
    __shared__ float red[2][4][4];   // per-row: {T,A0,A1,A2}, double-buffered

    // ---- issue row-0 x loads FIRST so the HBM stream starts immediately ----
    v4 xv[PASSES], xn[PASSES];
    {
        const float* xr = x + (size_t)blockIdx.x * D;
#pragma unroll
        for (int p = 0; p < PASSES; ++p)
            xv[p] = *reinterpret_cast<const v4*>(xr + p * (THREADS * VEC) + col);
    }

    // ---- prologue: block-invariant W and b (L2-hot cached loads) ----
    v4 wv[L][PASSES];
    v4 bs[PASSES];
    float bred[3] = {0.f, 0.f, 0.f};

#pragma unroll
    for (int p = 0; p < PASSES; ++p) {
        const int d = p * (THREADS * VEC) + col;
        v4 bsum = {0.f, 0.f, 0.f, 0.f};
#pragma unroll
        for (int i = 0; i < L; ++i) {
            wv[i][p] = *reinterpret_cast<const v4*>(W + i * D + d);
            v4 bb = *reinterpret_cast<const v4*>(b + i * D + d);
            bsum += bb;
            if (i < 3) bred[i] += hsum(bb);
        }
        bs[p] = bsum;
    }

#pragma unroll
    for (int k = 0; k < 3; ++k)
#pragma unroll
        for (int off = 32; off > 0; off >>= 1)
            bred[k] += __shfl_down(bred[k], off, 64);
    if (lane == 0)
#pragma unroll
        for (int k = 0; k < 3; ++k) redp[wid][k] = bred[k];
    __syncthreads();
    float Bsc[3];
#pragma unroll
    for (int k = 0; k < 3; ++k)
        Bsc[k] = redp[0][k] + redp[1][k] + redp[2][k] + redp[3][k];

    // ---- row loop: 1 row per iteration, prefetch next row ----
#pragma unroll
    for (int k = 0; k < RPB; ++k) {
        if (k + 1 < RPB) {
            const float* xr = x + (size_t)(blockIdx.x + GRID * (k + 1)) * D;
#pragma unroll
            for (int p = 0; p < PASSES; ++p)
                xn[p] = *reinterpret_cast<const v4*>(xr + p * (THREADS * VEC) + col);
        }

        // 4 row sums: T, A0, A1, A2
        float sm[4] = {0.f, 0.f, 0.f, 0.f};
#pragma unroll
        for (int p = 0; p < PASSES; ++p) {
            sm[0] += hsum(xv[p]);
#pragma unroll
            for (int i = 0; i < 3; ++i)
                sm[1 + i] += hsum(xv[p] * wv[i][p]);
        }
#pragma unroll
        for (int q = 0; q < 4; ++q)
#pragma unroll
            for (int off = 32; off > 0; off >>= 1)
                sm[q] += __shfl_down(sm[q], off, 64);

        if (lane == 0)
#pragma unroll
            for (int q = 0; q < 4; ++q) red[k & 1][wid][q] = sm[q];
        __syncthreads();
        // Safe single barrier: each wave reads red[k&1] below BEFORE its
        // next barrier, and iteration k+1 writes the OTHER buffer, so the
        // k+2 overwrite of red[k&1] is ordered behind every read.

        const float T = red[k & 1][0][0] + red[k & 1][1][0]
                      + red[k & 1][2][0] + red[k & 1][3][0];
        float A[3];
#pragma unroll
        for (int q = 0; q < 3; ++q)
            A[q] = red[k & 1][0][1 + q] + red[k & 1][1][1 + q]
                 + red[k & 1][2][1 + q] + red[k & 1][3][1 + q];

        float s[L];
        s[0] = T;
#pragma unroll
        for (int i = 1; i < L; ++i)
            s[i] = s[i - 1] * (1.f + A[i - 1]) + Bsc[i - 1];

        float* outr = out + (size_t)(blockIdx.x + GRID * k) * D;
#pragma unroll
        for (int p = 0; p < PASSES; ++p) {
            v4 c = {1.f, 1.f, 1.f, 1.f};
#pragma unroll
            for (int i = 0; i < L; ++i)
                c += s[i] * wv[i][p];
            *reinterpret_cast<v4*>(outr + p * (THREADS * VEC) + col) = xv[p] * c + bs[p];
        }

#pragma unroll
        for (int p = 0; p < PASSES; ++p) xv[p] = xn[p];
    }
}

extern "C" void kernel_launch(void* const* d_in, const int* in_sizes, int n_in,
                              void* d_out, int out_size, void* d_ws, size_t ws_size,
                              hipStream_t stream) {
    const float* x = (const float*)d_in[0];
    const float* W = (const float*)d_in[1];
    const float* b = (const float*)d_in[2];
    float* out = (float*)d_out;
    cross_layer_kernel<<<GRID, THREADS, 0, stream>>>(x, W, b, out);
}